// Round 9
// baseline (1375.698 us; speedup 1.0000x reference)
//
#include <hip/hip_runtime.h>
#include <hip/hip_bf16.h>

#define NN 100000
#define EE 400000
#define GG 1024

typedef _Float16 half_t;
typedef _Float16 f16x8 __attribute__((ext_vector_type(8)));
typedef float f32x4 __attribute__((ext_vector_type(4)));
typedef float f32x2 __attribute__((ext_vector_type(2)));

#define GLOAD_LDS(g, l) \
    __builtin_amdgcn_global_load_lds((const __attribute__((address_space(1))) void*)(g), \
                                     (__attribute__((address_space(3))) void*)(l), 16, 0, 0)

// ---------------- merged CSR build (both encoders as one 2N-node graph) ----------------

__global__ void k_count2(const int* __restrict__ ei1, const int* __restrict__ ei2,
                         int* __restrict__ deg) {
    int e = blockIdx.x * 256 + threadIdx.x;
    if (e >= 2 * EE) return;
    int enc = e >= EE;
    const int* ei = enc ? ei2 : ei1;
    int le = e - enc * EE;
    atomicAdd(&deg[enc * NN + ei[EE + le]], 1);
}

__global__ void k_scan_bsum(const int* __restrict__ deg, int* __restrict__ bsum, int total) {
    __shared__ int lds[256];
    int t = threadIdx.x;
    int base = blockIdx.x * 1024 + t * 4;
    int s = 0;
#pragma unroll
    for (int i = 0; i < 4; ++i) { int idx = base + i; s += (idx < total) ? deg[idx] : 0; }
    lds[t] = s;
    __syncthreads();
    for (int off = 128; off > 0; off >>= 1) {
        if (t < off) lds[t] += lds[t + off];
        __syncthreads();
    }
    if (t == 0) bsum[blockIdx.x] = lds[0];
}

__global__ void k_scan_write(const int* __restrict__ deg, const int* __restrict__ bsum,
                             int* __restrict__ rowptr, float* __restrict__ dinv,
                             int total, int totedge) {
    __shared__ int lds[256];
    __shared__ int blockoff;
    int t = threadIdx.x;
    if (t == 0) {
        int off = 0;
        for (int b = 0; b < (int)blockIdx.x; ++b) off += bsum[b];
        blockoff = off;
    }
    int base = blockIdx.x * 1024 + t * 4;
    int v[4]; int ts = 0;
#pragma unroll
    for (int i = 0; i < 4; ++i) { int idx = base + i; v[i] = (idx < total) ? deg[idx] : 0; ts += v[i]; }
    lds[t] = ts;
    __syncthreads();
    for (int off = 1; off < 256; off <<= 1) {
        int x = (t >= off) ? lds[t - off] : 0;
        __syncthreads();
        lds[t] += x;
        __syncthreads();
    }
    int excl = lds[t] - ts + blockoff;
#pragma unroll
    for (int i = 0; i < 4; ++i) {
        int idx = base + i;
        if (idx < total) {
            rowptr[idx] = excl;
            dinv[idx] = rsqrtf((float)v[i] + 1.0f);
        }
        excl += v[i];
    }
    if (blockIdx.x == 0 && t == 0) rowptr[total] = totedge;
}

__global__ void k_fill2(const int* __restrict__ ei1, const int* __restrict__ ei2,
                        const int* __restrict__ rowptr, int* __restrict__ cnt,
                        int* __restrict__ colv) {
    int e = blockIdx.x * 256 + threadIdx.x;
    if (e >= 2 * EE) return;
    int enc = e >= EE;
    const int* ei = enc ? ei2 : ei1;
    int le = e - enc * EE;
    int s = ei[le], d = ei[EE + le];
    int gd = enc * NN + d;
    int pos = rowptr[gd] + atomicAdd(&cnt[gd], 1);
    colv[pos] = s;   // local source id
}

__global__ void k_starts2(const int* __restrict__ b1, const int* __restrict__ b2,
                          int* __restrict__ gstart) {
    int i = blockIdx.x * 256 + threadIdx.x;
    if (i >= 2 * NN) return;
    int enc = i >= NN;
    int il = i - enc * NN;
    const int* bat = enc ? b2 : b1;
    int* gs = gstart + enc * (GG + 1);
    int b = bat[il];
    if (il == 0) {
        for (int g = 0; g <= b; ++g) gs[g] = 0;
    } else {
        int pb = bat[il - 1];
        for (int g = pb + 1; g <= b; ++g) gs[g] = il;
    }
    if (il == NN - 1) {
        for (int g = b + 1; g <= GG; ++g) gs[g] = NN;
    }
}

// ---------------- aggregation + f16 hi/lo split ----------------

// F=90: rows 360B (float2-aligned). 45 lanes x float2, 4-way neighbor unroll. KPAD=128.
__global__ void k_agg90(const float* __restrict__ x, const float* __restrict__ dinv,
                        const int* __restrict__ rowptr, const int* __restrict__ col,
                        half_t* __restrict__ out) {
    int wave = threadIdx.x >> 6;
    int lane = threadIdx.x & 63;
    int n = blockIdx.x * 4 + wave;
    if (n >= NN) return;
    bool al = lane < 45;
    float dn = dinv[n];
    f32x2 acc = {0.f, 0.f};
    if (al) acc = dn * ((const f32x2*)(x + (size_t)n * 90))[lane];
    int j0 = rowptr[n], j1 = rowptr[n + 1];
    int j = j0;
    for (; j + 4 <= j1; j += 4) {
        int s0 = col[j], s1 = col[j + 1], s2 = col[j + 2], s3 = col[j + 3];
        float d0 = dinv[s0], d1 = dinv[s1], d2 = dinv[s2], d3 = dinv[s3];
        if (al) {
            f32x2 v0 = ((const f32x2*)(x + (size_t)s0 * 90))[lane];
            f32x2 v1 = ((const f32x2*)(x + (size_t)s1 * 90))[lane];
            f32x2 v2 = ((const f32x2*)(x + (size_t)s2 * 90))[lane];
            f32x2 v3 = ((const f32x2*)(x + (size_t)s3 * 90))[lane];
            acc += d0 * v0; acc += d1 * v1; acc += d2 * v2; acc += d3 * v3;
        }
    }
    for (; j < j1; ++j) {
        int s = col[j];
        float ds = dinv[s];
        if (al) acc += ds * ((const f32x2*)(x + (size_t)s * 90))[lane];
    }
    float v0 = al ? dn * acc[0] : 0.f;
    float v1 = al ? dn * acc[1] : 0.f;
    half_t h0 = (half_t)v0, l0 = (half_t)(v0 - (float)h0);
    half_t h1 = (half_t)v1, l1 = (half_t)(v1 - (float)h1);
    half_t* o = out + (size_t)n * 256;
    o[2 * lane] = h0;
    o[2 * lane + 1] = h1;
    o[128 + 2 * lane] = l0;
    o[128 + 2 * lane + 1] = l1;
}

// Two nodes per wave: lanes 0-31 -> node A, lanes 32-63 -> node B.
// F = 32*VW. Uniform trip count max(degA,degB); dead slots predicated to self-row w=0.
// One gather instruction fetches a full row for BOTH nodes -> 2x memory-level parallelism.
// Accumulation order per node identical to sequential j-ascending (bitwise same result).
template <int VW>
__global__ void k_aggpair(const float* __restrict__ x, const float* __restrict__ dinv,
                          const int* __restrict__ rowptr, const int* __restrict__ col,
                          half_t* __restrict__ out) {
    constexpr int F = 32 * VW;
    typedef float fvec __attribute__((ext_vector_type(VW)));
    int wave = threadIdx.x >> 6;
    int lane = threadIdx.x & 63;
    int sub = lane & 31;
    int n = blockIdx.x * 8 + wave * 2 + (lane >> 5);   // NN % 8 == 0: always in range
    float dn = dinv[n];
    fvec acc = dn * ((const fvec*)(x + (size_t)n * F))[sub];
    int j0 = rowptr[n];
    int deg = rowptr[n + 1] - j0;
    int m = max(deg, __shfl_xor(deg, 32));
    int t = 0;
    for (; t + 4 <= m; t += 4) {
        bool o0 = t < deg, o1 = t + 1 < deg, o2 = t + 2 < deg, o3 = t + 3 < deg;
        int s0 = o0 ? col[j0 + t]     : n;
        int s1 = o1 ? col[j0 + t + 1] : n;
        int s2 = o2 ? col[j0 + t + 2] : n;
        int s3 = o3 ? col[j0 + t + 3] : n;
        float w0 = o0 ? dinv[s0] : 0.f;
        float w1 = o1 ? dinv[s1] : 0.f;
        float w2 = o2 ? dinv[s2] : 0.f;
        float w3 = o3 ? dinv[s3] : 0.f;
        fvec v0 = ((const fvec*)(x + (size_t)s0 * F))[sub];
        fvec v1 = ((const fvec*)(x + (size_t)s1 * F))[sub];
        fvec v2 = ((const fvec*)(x + (size_t)s2 * F))[sub];
        fvec v3 = ((const fvec*)(x + (size_t)s3 * F))[sub];
        acc += w0 * v0; acc += w1 * v1; acc += w2 * v2; acc += w3 * v3;
    }
    if (t < m) {   // 1..3 remaining on the longer node; parallel predicated block
        bool o0 = t < deg, o1 = t + 1 < deg, o2 = t + 2 < deg;
        bool m1 = t + 1 < m, m2 = t + 2 < m;
        int s0 = o0 ? col[j0 + t]     : n;
        int s1 = o1 ? col[j0 + t + 1] : n;
        int s2 = o2 ? col[j0 + t + 2] : n;
        float w0 = o0 ? dinv[s0] : 0.f;
        float w1 = o1 ? dinv[s1] : 0.f;
        float w2 = o2 ? dinv[s2] : 0.f;
        fvec v0 = ((const fvec*)(x + (size_t)s0 * F))[sub];
        acc += w0 * v0;
        if (m1) { fvec v1 = ((const fvec*)(x + (size_t)s1 * F))[sub]; acc += w1 * v1; }
        if (m2) { fvec v2 = ((const fvec*)(x + (size_t)s2 * F))[sub]; acc += w2 * v2; }
    }
    half_t* o = out + (size_t)n * (2 * F);
#pragma unroll
    for (int i = 0; i < VW; ++i) {
        float v = dn * acc[i];
        half_t h = (half_t)v;
        half_t l = (half_t)(v - (float)h);
        o[sub * VW + i] = h;
        o[F + sub * VW + i] = l;
    }
}

// ---------------- weight prep: Bt[Nc][3*Kpad] = [Whi | Whi | Wlo] (transposed) -------

__global__ void k_wprep(const float* __restrict__ W, half_t* __restrict__ Bt,
                        int K, int Kpad, int Nc) {
    int t = blockIdx.x * 256 + threadIdx.x;
    if (t >= Nc * Kpad) return;
    int n = t / Kpad, kp = t % Kpad;
    half_t h = (half_t)0.f, l = (half_t)0.f;
    if (kp < K) {
        float w = W[(size_t)kp * Nc + n];
        h = (half_t)w;
        l = (half_t)(w - (float)h);
    }
    half_t* o = Bt + (size_t)n * 3 * Kpad;
    o[kp] = h;
    o[Kpad + kp] = h;
    o[2 * Kpad + kp] = l;
}

__global__ void k_split(const float* __restrict__ in, half_t* __restrict__ out, int K) {
    int t = blockIdx.x * 256 + threadIdx.x;
    int row = t / K, k = t % K;
    float v = in[t];
    half_t h = (half_t)v;
    half_t l = (half_t)(v - (float)h);
    half_t* o = out + (size_t)row * 2 * K;
    o[k] = h;
    o[K + k] = l;
}

// ---------------- MFMA GEMM, BN=128 (L1 + head) ----------------
// augmented-K split-precision sweep; 128x128 tile, 4 waves, 16x16x32 f16 MFMA, BK=64.

template <bool RELU>
__global__ __launch_bounds__(256, 2)
void k_mgemm(const half_t* __restrict__ Ap, const half_t* __restrict__ Bt,
             const float* __restrict__ bias, float* __restrict__ C,
             int M, int Kpad, int Nc) {
    __shared__ half_t As[128 * 64];
    __shared__ half_t Bs[128 * 64];
    const int tid = threadIdx.x;
    const int wave = tid >> 6, lane = tid & 63;
    const int wm = wave >> 1, wn = wave & 1;
    const int bm = blockIdx.x * 128, bn = blockIdx.y * 128;
    const int KA = 2 * Kpad, KB = 3 * Kpad;
    const int nkt = KB >> 6;
    const int aTiles = KA >> 6;

    f32x4 acc[4][4] = {};

    const int srow = tid >> 3;
    const int ch = tid & 7;

    for (int kt = 0; kt < nkt; ++kt) {
        int ka0 = ((kt < aTiles) ? kt : (kt - aTiles)) << 6;
        int kb0 = kt << 6;
        __syncthreads();
#pragma unroll
        for (int i = 0; i < 4; ++i) {
            int rl = i * 32 + srow;
            int sch = ch ^ (rl & 7);
            int gr = bm + rl; if (gr >= M) gr = M - 1;
            const half_t* ga = Ap + (size_t)gr * KA + ka0 + sch * 8;
            GLOAD_LDS(ga, (char*)As + i * 4096 + wave * 1024);
        }
#pragma unroll
        for (int i = 0; i < 4; ++i) {
            int rl = i * 32 + srow;
            int sch = ch ^ (rl & 7);
            const half_t* gb = Bt + (size_t)(bn + rl) * KB + kb0 + sch * 8;
            GLOAD_LDS(gb, (char*)Bs + i * 4096 + wave * 1024);
        }
        __syncthreads();
#pragma unroll
        for (int s = 0; s < 2; ++s) {
            f16x8 af[4], bf[4];
#pragma unroll
            for (int i = 0; i < 4; ++i) {
                int row = wm * 64 + i * 16 + (lane & 15);
                int c = s * 4 + (lane >> 4);
                af[i] = *(const f16x8*)&As[row * 64 + ((c ^ (row & 7)) << 3)];
            }
#pragma unroll
            for (int j = 0; j < 4; ++j) {
                int row = wn * 64 + j * 16 + (lane & 15);
                int c = s * 4 + (lane >> 4);
                bf[j] = *(const f16x8*)&Bs[row * 64 + ((c ^ (row & 7)) << 3)];
            }
#pragma unroll
            for (int i = 0; i < 4; ++i)
#pragma unroll
                for (int j = 0; j < 4; ++j)
                    acc[i][j] = __builtin_amdgcn_mfma_f32_16x16x32_f16(af[i], bf[j], acc[i][j], 0, 0, 0);
        }
    }

#pragma unroll
    for (int i = 0; i < 4; ++i) {
#pragma unroll
        for (int j = 0; j < 4; ++j) {
            int cc = bn + wn * 64 + j * 16 + (lane & 15);
            float bv = bias[cc];
            int r0 = bm + wm * 64 + i * 16 + (lane >> 4) * 4;
#pragma unroll
            for (int q = 0; q < 4; ++q) {
                int gr = r0 + q;
                if (gr < M) {
                    float v = acc[i][j][q] + bv;
                    if (RELU) v = fmaxf(v, 0.f);
                    C[(size_t)gr * Nc + cc] = v;
                }
            }
        }
    }
}

// ---------------- MFMA GEMM, BN=256 (node layers L2-L4, Nc==256) ----------------
// One block covers ALL 256 output cols for its 128-row panel -> A read exactly once
// per sweep (halves A traffic vs BN=128). Same staging/swizzle/k-sweep as k_mgemm.

template <bool RELU>
__global__ __launch_bounds__(256, 2)
void k_mgemm256(const half_t* __restrict__ Ap, const half_t* __restrict__ Bt,
                const float* __restrict__ bias, float* __restrict__ C,
                int M, int Kpad) {
    __shared__ half_t As[128 * 64];
    __shared__ half_t Bs[256 * 64];
    const int tid = threadIdx.x;
    const int wave = tid >> 6, lane = tid & 63;
    const int wm = wave >> 1, wn = wave & 1;   // rows: wm*64; cols: wn*128
    const int bm = blockIdx.x * 128;
    const int KA = 2 * Kpad, KB = 3 * Kpad;
    const int nkt = KB >> 6;
    const int aTiles = KA >> 6;

    f32x4 acc[4][8] = {};

    const int srow = tid >> 3;
    const int ch = tid & 7;

    for (int kt = 0; kt < nkt; ++kt) {
        int ka0 = ((kt < aTiles) ? kt : (kt - aTiles)) << 6;
        int kb0 = kt << 6;
        __syncthreads();
#pragma unroll
        for (int i = 0; i < 4; ++i) {
            int rl = i * 32 + srow;
            int sch = ch ^ (rl & 7);
            int gr = bm + rl; if (gr >= M) gr = M - 1;
            const half_t* ga = Ap + (size_t)gr * KA + ka0 + sch * 8;
            GLOAD_LDS(ga, (char*)As + i * 4096 + wave * 1024);
        }
#pragma unroll
        for (int i = 0; i < 8; ++i) {
            int rl = i * 32 + srow;                 // Bt row (output col) 0..255
            int sch = ch ^ (rl & 7);
            const half_t* gb = Bt + (size_t)rl * KB + kb0 + sch * 8;
            GLOAD_LDS(gb, (char*)Bs + i * 4096 + wave * 1024);
        }
        __syncthreads();
#pragma unroll
        for (int s = 0; s < 2; ++s) {
            f16x8 af[4], bf[8];
#pragma unroll
            for (int i = 0; i < 4; ++i) {
                int row = wm * 64 + i * 16 + (lane & 15);
                int c = s * 4 + (lane >> 4);
                af[i] = *(const f16x8*)&As[row * 64 + ((c ^ (row & 7)) << 3)];
            }
#pragma unroll
            for (int j = 0; j < 8; ++j) {
                int row = wn * 128 + j * 16 + (lane & 15);
                int c = s * 4 + (lane >> 4);
                bf[j] = *(const f16x8*)&Bs[row * 64 + ((c ^ (row & 7)) << 3)];
            }
#pragma unroll
            for (int i = 0; i < 4; ++i)
#pragma unroll
                for (int j = 0; j < 8; ++j)
                    acc[i][j] = __builtin_amdgcn_mfma_f32_16x16x32_f16(af[i], bf[j], acc[i][j], 0, 0, 0);
        }
    }

#pragma unroll
    for (int i = 0; i < 4; ++i) {
#pragma unroll
        for (int j = 0; j < 8; ++j) {
            int cc = wn * 128 + j * 16 + (lane & 15);
            float bv = bias[cc];
            int r0 = bm + wm * 64 + i * 16 + (lane >> 4) * 4;
#pragma unroll
            for (int q = 0; q < 4; ++q) {
                int gr = r0 + q;
                if (gr < M) {
                    float v = acc[i][j][q] + bv;
                    if (RELU) v = fmaxf(v, 0.f);
                    C[(size_t)gr * 256 + cc] = v;
                }
            }
        }
    }
}

// ---------------- pooling ----------------

__global__ void k_pool(const float* __restrict__ act, const int* __restrict__ gstart,
                       float* __restrict__ h) {
    int g = blockIdx.x;
    int f = threadIdx.x;
    int s = gstart[g], e = gstart[g + 1];
    float mx = 0.f, sm = 0.f;
    for (int i = s; i < e; ++i) {
        float v = act[(size_t)i * 256 + f];
        mx = fmaxf(mx, v);
        sm += v;
    }
    float cnt = (float)(e - s);
    h[(size_t)g * 512 + f] = mx;
    h[(size_t)g * 512 + 256 + f] = (cnt > 0.f) ? sm / cnt : 0.f;
}

// ---------------- head ----------------

__global__ void k_headin_split(const float* __restrict__ h, half_t* __restrict__ xh) {
    int t = blockIdx.x * blockDim.x + threadIdx.x;
    if (t >= GG * 1024) return;
    int g = t >> 10, j = t & 1023;
    const float* h1 = h + (size_t)g * 512;
    const float* h2 = h + (size_t)(GG + g) * 512;
    float v = (j < 512) ? (h1[j] - h2[j]) : (h2[j - 512] - h1[j - 512]);
    half_t hi = (half_t)v;
    half_t lo = (half_t)(v - (float)hi);
    half_t* o = xh + (size_t)g * 2048;
    o[j] = hi;
    o[1024 + j] = lo;
}

__global__ void k_fc3(const float* __restrict__ A, const float* __restrict__ W,
                      const float* __restrict__ b, float* __restrict__ out) {
    int g = blockIdx.x * 4 + (threadIdx.x >> 6);
    int lane = threadIdx.x & 63;
    const float* a = A + (size_t)g * 256;
    float p = a[lane] * W[lane] + a[lane + 64] * W[lane + 64]
            + a[lane + 128] * W[lane + 128] + a[lane + 192] * W[lane + 192];
    for (int off = 32; off > 0; off >>= 1) p += __shfl_down(p, off);
    if (lane == 0) out[g] = tanhf(p + b[0]);
}

// ---------------- launch ----------------

extern "C" void kernel_launch(void* const* d_in, const int* in_sizes, int n_in,
                              void* d_out, int out_size, void* d_ws, size_t ws_size,
                              hipStream_t stream) {
    const float* x1  = (const float*)d_in[0];
    const int*   ei1 = (const int*)d_in[1];
    const int*   ba1 = (const int*)d_in[2];
    const float* x2  = (const float*)d_in[3];
    const int*   ei2 = (const int*)d_in[4];
    const int*   ba2 = (const int*)d_in[5];
    const float* W1 = (const float*)d_in[6];
    const float* b1 = (const float*)d_in[7];
    const float* W2 = (const float*)d_in[8];
    const float* b2 = (const float*)d_in[9];
    const float* W3 = (const float*)d_in[10];
    const float* b3 = (const float*)d_in[11];
    const float* W4 = (const float*)d_in[12];
    const float* b4 = (const float*)d_in[13];
    const float* fc1W = (const float*)d_in[14];
    const float* fc1b = (const float*)d_in[15];
    const float* fc2W = (const float*)d_in[16];
    const float* fc2b = (const float*)d_in[17];
    const float* fc3W = (const float*)d_in[18];
    const float* fc3b = (const float*)d_in[19];
    float* out = (float*)d_out;

    char* ws = (char*)d_ws;
    size_t off = 0;
    auto alloc = [&](size_t bytes) -> void* {
        void* p = (void*)(ws + off);
        off += (bytes + 255) & ~(size_t)255;
        return p;
    };
    int*    dc     = (int*)alloc((size_t)4 * NN * sizeof(int));   // deg[2N] | cnt[2N]
    int*    rowptr = (int*)alloc((size_t)(2 * NN + 1) * sizeof(int));
    int*    colv   = (int*)alloc((size_t)2 * EE * sizeof(int));
    int*    bsum   = (int*)alloc(256 * sizeof(int));
    int*    gstart = (int*)alloc((size_t)2 * (GG + 1) * sizeof(int));
    float*  dinv   = (float*)alloc((size_t)2 * NN * sizeof(float));
    half_t* Ap     = (half_t*)alloc((size_t)NN * 512 * sizeof(half_t));
    float*  act    = (float*)alloc((size_t)NN * 256 * sizeof(float));
    half_t* Bt1    = (half_t*)alloc((size_t)128 * 384 * sizeof(half_t));
    half_t* Bt2    = (half_t*)alloc((size_t)256 * 384 * sizeof(half_t));
    half_t* Bt3    = (half_t*)alloc((size_t)256 * 768 * sizeof(half_t));
    half_t* Bt4    = (half_t*)alloc((size_t)256 * 768 * sizeof(half_t));
    half_t* Btf1   = (half_t*)alloc((size_t)512 * 3072 * sizeof(half_t));
    half_t* Btf2   = (half_t*)alloc((size_t)256 * 1536 * sizeof(half_t));
    float*  hpool  = (float*)alloc((size_t)2 * GG * 512 * sizeof(float));
    half_t* xhs    = (half_t*)alloc((size_t)GG * 2048 * sizeof(half_t));
    float*  t1     = (float*)alloc((size_t)GG * 512 * sizeof(float));
    half_t* t1s    = (half_t*)alloc((size_t)GG * 1024 * sizeof(half_t));
    float*  t2     = (float*)alloc((size_t)GG * 256 * sizeof(float));

    int* deg = dc;
    int* cnt = dc + 2 * NN;

    int nsb2 = (2 * NN + 1023) / 1024;
    int mt = (NN + 127) / 128;           // 782

    // weight prep (shared across both encoders + head)
    k_wprep<<<(128 * 128 + 255) / 256, 256, 0, stream>>>(W1, Bt1, 90, 128, 128);
    k_wprep<<<(256 * 128 + 255) / 256, 256, 0, stream>>>(W2, Bt2, 128, 128, 256);
    k_wprep<<<(256 * 256 + 255) / 256, 256, 0, stream>>>(W3, Bt3, 256, 256, 256);
    k_wprep<<<(256 * 256 + 255) / 256, 256, 0, stream>>>(W4, Bt4, 256, 256, 256);
    k_wprep<<<(512 * 1024 + 255) / 256, 256, 0, stream>>>(fc1W, Btf1, 1024, 1024, 512);
    k_wprep<<<(256 * 512 + 255) / 256, 256, 0, stream>>>(fc2W, Btf2, 512, 512, 256);

    // merged CSR build (once for both encoders)
    hipMemsetAsync(dc, 0, (size_t)4 * NN * sizeof(int), stream);
    k_count2<<<(2 * EE + 255) / 256, 256, 0, stream>>>(ei1, ei2, deg);
    k_scan_bsum<<<nsb2, 256, 0, stream>>>(deg, bsum, 2 * NN);
    k_scan_write<<<nsb2, 256, 0, stream>>>(deg, bsum, rowptr, dinv, 2 * NN, 2 * EE);
    k_fill2<<<(2 * EE + 255) / 256, 256, 0, stream>>>(ei1, ei2, rowptr, cnt, colv);
    k_starts2<<<(2 * NN + 255) / 256, 256, 0, stream>>>(ba1, ba2, gstart);

    for (int p = 0; p < 2; ++p) {
        const float* x  = p ? x2 : x1;
        const int*   rp = rowptr + p * NN;
        const float* dv = dinv + p * NN;
        const int*   gs = gstart + p * (GG + 1);

        // L1: agg90 -> Ap[N][256]h; BN=128 gemm -> act[N,128]
        k_agg90<<<(NN + 3) / 4, 256, 0, stream>>>(x, dv, rp, colv, Ap);
        k_mgemm<true><<<dim3(mt, 1), 256, 0, stream>>>(Ap, Bt1, b1, act, NN, 128, 128);
        // L2: F=128 pair-gather -> Ap[N][256]h; BN=256 gemm -> act[N,256]
        k_aggpair<4><<<NN / 8, 256, 0, stream>>>(act, dv, rp, colv, Ap);
        k_mgemm256<true><<<mt, 256, 0, stream>>>(Ap, Bt2, b2, act, NN, 128);
        // L3: F=256 pair-gather -> Ap[N][512]h; BN=256 gemm
        k_aggpair<8><<<NN / 8, 256, 0, stream>>>(act, dv, rp, colv, Ap);
        k_mgemm256<true><<<mt, 256, 0, stream>>>(Ap, Bt3, b3, act, NN, 256);
        // L4
        k_aggpair<8><<<NN / 8, 256, 0, stream>>>(act, dv, rp, colv, Ap);
        k_mgemm256<true><<<mt, 256, 0, stream>>>(Ap, Bt4, b4, act, NN, 256);

        k_pool<<<GG, 256, 0, stream>>>(act, gs, hpool + (size_t)p * GG * 512);
    }

    // head: split-precision MFMA for fc1/fc2, wave-reduce for fc3
    k_headin_split<<<(GG * 1024 + 255) / 256, 256, 0, stream>>>(hpool, xhs);
    k_mgemm<true><<<dim3(GG / 128, 4), 256, 0, stream>>>(xhs, Btf1, fc1b, t1, GG, 1024, 512);
    k_split<<<(GG * 512 + 255) / 256, 256, 0, stream>>>(t1, t1s, 512);
    k_mgemm<true><<<dim3(GG / 128, 2), 256, 0, stream>>>(t1s, Btf2, fc2b, t2, GG, 512, 256);
    k_fc3<<<GG / 4, 256, 0, stream>>>(t2, fc3W, fc3b, out);
}

// Round 10
// 1331.385 us; speedup vs baseline: 1.0333x; 1.0333x over previous
//
#include <hip/hip_runtime.h>
#include <hip/hip_bf16.h>

#define NN 100000
#define EE 400000
#define GG 1024

typedef _Float16 half_t;
typedef _Float16 f16x8 __attribute__((ext_vector_type(8)));
typedef float f32x4 __attribute__((ext_vector_type(4)));
typedef float f32x2 __attribute__((ext_vector_type(2)));

#define GLOAD_LDS(g, l) \
    __builtin_amdgcn_global_load_lds((const __attribute__((address_space(1))) void*)(g), \
                                     (__attribute__((address_space(3))) void*)(l), 16, 0, 0)

// ---------------- merged CSR build (both encoders as one 2N-node graph) ----------------

__global__ void k_count2(const int* __restrict__ ei1, const int* __restrict__ ei2,
                         int* __restrict__ deg) {
    int e = blockIdx.x * 256 + threadIdx.x;
    if (e >= 2 * EE) return;
    int enc = e >= EE;
    const int* ei = enc ? ei2 : ei1;
    int le = e - enc * EE;
    atomicAdd(&deg[enc * NN + ei[EE + le]], 1);
}

__global__ void k_scan_bsum(const int* __restrict__ deg, int* __restrict__ bsum, int total) {
    __shared__ int lds[256];
    int t = threadIdx.x;
    int base = blockIdx.x * 1024 + t * 4;
    int s = 0;
#pragma unroll
    for (int i = 0; i < 4; ++i) { int idx = base + i; s += (idx < total) ? deg[idx] : 0; }
    lds[t] = s;
    __syncthreads();
    for (int off = 128; off > 0; off >>= 1) {
        if (t < off) lds[t] += lds[t + off];
        __syncthreads();
    }
    if (t == 0) bsum[blockIdx.x] = lds[0];
}

// single block: exclusive scan of bsum[0..nb) -> boff
__global__ void k_scan_off(const int* __restrict__ bsum, int* __restrict__ boff, int nb) {
    __shared__ int lds[256];
    int t = threadIdx.x;
    int v = (t < nb) ? bsum[t] : 0;
    lds[t] = v;
    __syncthreads();
    for (int off = 1; off < 256; off <<= 1) {
        int x = (t >= off) ? lds[t - off] : 0;
        __syncthreads();
        lds[t] += x;
        __syncthreads();
    }
    if (t < nb) boff[t] = lds[t] - v;   // exclusive
}

__global__ void k_scan_write(const int* __restrict__ deg, const int* __restrict__ boff,
                             int* __restrict__ rowptr, float* __restrict__ dinv,
                             int total, int totedge) {
    __shared__ int lds[256];
    int t = threadIdx.x;
    int blockoff = boff[blockIdx.x];
    int base = blockIdx.x * 1024 + t * 4;
    int v[4]; int ts = 0;
#pragma unroll
    for (int i = 0; i < 4; ++i) { int idx = base + i; v[i] = (idx < total) ? deg[idx] : 0; ts += v[i]; }
    lds[t] = ts;
    __syncthreads();
    for (int off = 1; off < 256; off <<= 1) {
        int x = (t >= off) ? lds[t - off] : 0;
        __syncthreads();
        lds[t] += x;
        __syncthreads();
    }
    int excl = lds[t] - ts + blockoff;
#pragma unroll
    for (int i = 0; i < 4; ++i) {
        int idx = base + i;
        if (idx < total) {
            rowptr[idx] = excl;
            dinv[idx] = rsqrtf((float)v[i] + 1.0f);
        }
        excl += v[i];
    }
    if (blockIdx.x == 0 && t == 0) rowptr[total] = totedge;
}

__global__ void k_fill2(const int* __restrict__ ei1, const int* __restrict__ ei2,
                        const int* __restrict__ rowptr, int* __restrict__ cnt,
                        int* __restrict__ colv) {
    int e = blockIdx.x * 256 + threadIdx.x;
    if (e >= 2 * EE) return;
    int enc = e >= EE;
    const int* ei = enc ? ei2 : ei1;
    int le = e - enc * EE;
    int s = ei[le], d = ei[EE + le];
    int gd = enc * NN + d;
    int pos = rowptr[gd] + atomicAdd(&cnt[gd], 1);
    colv[pos] = s;   // local source id
}

__global__ void k_starts2(const int* __restrict__ b1, const int* __restrict__ b2,
                          int* __restrict__ gstart) {
    int i = blockIdx.x * 256 + threadIdx.x;
    if (i >= 2 * NN) return;
    int enc = i >= NN;
    int il = i - enc * NN;
    const int* bat = enc ? b2 : b1;
    int* gs = gstart + enc * (GG + 1);
    int b = bat[il];
    if (il == 0) {
        for (int g = 0; g <= b; ++g) gs[g] = 0;
    } else {
        int pb = bat[il - 1];
        for (int g = pb + 1; g <= b; ++g) gs[g] = il;
    }
    if (il == NN - 1) {
        for (int g = b + 1; g <= GG; ++g) gs[g] = NN;
    }
}

// ---------------- aggregation + f16 hi/lo split ----------------

// F=90: rows 360B (float2-aligned). 45 lanes x float2, 4-way neighbor unroll. KPAD=128.
__global__ void k_agg90(const float* __restrict__ x, const float* __restrict__ dinv,
                        const int* __restrict__ rowptr, const int* __restrict__ col,
                        half_t* __restrict__ out) {
    int wave = threadIdx.x >> 6;
    int lane = threadIdx.x & 63;
    int n = blockIdx.x * 4 + wave;
    if (n >= NN) return;
    bool al = lane < 45;
    float dn = dinv[n];
    f32x2 acc = {0.f, 0.f};
    if (al) acc = dn * ((const f32x2*)(x + (size_t)n * 90))[lane];
    int j0 = rowptr[n], j1 = rowptr[n + 1];
    int j = j0;
    for (; j + 4 <= j1; j += 4) {
        int s0 = col[j], s1 = col[j + 1], s2 = col[j + 2], s3 = col[j + 3];
        float d0 = dinv[s0], d1 = dinv[s1], d2 = dinv[s2], d3 = dinv[s3];
        if (al) {
            f32x2 v0 = ((const f32x2*)(x + (size_t)s0 * 90))[lane];
            f32x2 v1 = ((const f32x2*)(x + (size_t)s1 * 90))[lane];
            f32x2 v2 = ((const f32x2*)(x + (size_t)s2 * 90))[lane];
            f32x2 v3 = ((const f32x2*)(x + (size_t)s3 * 90))[lane];
            acc += d0 * v0; acc += d1 * v1; acc += d2 * v2; acc += d3 * v3;
        }
    }
    for (; j < j1; ++j) {
        int s = col[j];
        float ds = dinv[s];
        if (al) acc += ds * ((const f32x2*)(x + (size_t)s * 90))[lane];
    }
    float v0 = al ? dn * acc[0] : 0.f;
    float v1 = al ? dn * acc[1] : 0.f;
    half_t h0 = (half_t)v0, l0 = (half_t)(v0 - (float)h0);
    half_t h1 = (half_t)v1, l1 = (half_t)(v1 - (float)h1);
    half_t* o = out + (size_t)n * 256;
    o[2 * lane] = h0;
    o[2 * lane + 1] = h1;
    o[128 + 2 * lane] = l0;
    o[128 + 2 * lane + 1] = l1;
}

// F = KPAD = 64*VW, one float-vector per lane, 4-way neighbor unroll. (round-7 proven)
template <int VW>
__global__ void k_agg_splitv(const float* __restrict__ x, const float* __restrict__ dinv,
                             const int* __restrict__ rowptr, const int* __restrict__ col,
                             half_t* __restrict__ out) {
    constexpr int F = 64 * VW;
    typedef float fvec __attribute__((ext_vector_type(VW)));
    int wave = threadIdx.x >> 6;
    int lane = threadIdx.x & 63;
    int n = blockIdx.x * 4 + wave;
    if (n >= NN) return;
    float dn = dinv[n];
    fvec acc = dn * ((const fvec*)(x + (size_t)n * F))[lane];
    int j0 = rowptr[n], j1 = rowptr[n + 1];
    int j = j0;
    for (; j + 4 <= j1; j += 4) {
        int s0 = col[j], s1 = col[j + 1], s2 = col[j + 2], s3 = col[j + 3];
        float d0 = dinv[s0], d1 = dinv[s1], d2 = dinv[s2], d3 = dinv[s3];
        fvec v0 = ((const fvec*)(x + (size_t)s0 * F))[lane];
        fvec v1 = ((const fvec*)(x + (size_t)s1 * F))[lane];
        fvec v2 = ((const fvec*)(x + (size_t)s2 * F))[lane];
        fvec v3 = ((const fvec*)(x + (size_t)s3 * F))[lane];
        acc += d0 * v0; acc += d1 * v1; acc += d2 * v2; acc += d3 * v3;
    }
    for (; j < j1; ++j) {
        int s = col[j];
        acc += dinv[s] * ((const fvec*)(x + (size_t)s * F))[lane];
    }
    half_t* o = out + (size_t)n * (2 * F);
    half_t hv[VW], lv[VW];
#pragma unroll
    for (int i = 0; i < VW; ++i) {
        float v = dn * acc[i];
        hv[i] = (half_t)v;
        lv[i] = (half_t)(v - (float)hv[i]);
    }
#pragma unroll
    for (int i = 0; i < VW; ++i) o[lane * VW + i] = hv[i];
#pragma unroll
    for (int i = 0; i < VW; ++i) o[F + lane * VW + i] = lv[i];
}

// ---------------- fused weight prep: all six matrices in one dispatch --------------
// Bt[Nc][3*Kpad] = [Whi | Whi | Wlo] (transposed)

__device__ __forceinline__ void wprep_one(const float* __restrict__ W, half_t* __restrict__ Bt,
                                          int K, int Kpad, int Nc, int t) {
    int n = t / Kpad, kp = t % Kpad;
    half_t h = (half_t)0.f, l = (half_t)0.f;
    if (kp < K) {
        float w = W[(size_t)kp * Nc + n];
        h = (half_t)w;
        l = (half_t)(w - (float)h);
    }
    half_t* o = Bt + (size_t)n * 3 * Kpad;
    o[kp] = h;
    o[Kpad + kp] = h;
    o[2 * Kpad + kp] = l;
}

__global__ void k_wprep_all(const float* __restrict__ W1, const float* __restrict__ W2,
                            const float* __restrict__ W3, const float* __restrict__ W4,
                            const float* __restrict__ F1, const float* __restrict__ F2,
                            half_t* __restrict__ B1, half_t* __restrict__ B2,
                            half_t* __restrict__ B3, half_t* __restrict__ B4,
                            half_t* __restrict__ Bf1, half_t* __restrict__ Bf2) {
    int t = blockIdx.x * 256 + threadIdx.x;
    if (t < 16384) { wprep_one(W1, B1, 90, 128, 128, t); return; }
    t -= 16384;
    if (t < 32768) { wprep_one(W2, B2, 128, 128, 256, t); return; }
    t -= 32768;
    if (t < 65536) { wprep_one(W3, B3, 256, 256, 256, t); return; }
    t -= 65536;
    if (t < 65536) { wprep_one(W4, B4, 256, 256, 256, t); return; }
    t -= 65536;
    if (t < 524288) { wprep_one(F1, Bf1, 1024, 1024, 512, t); return; }
    t -= 524288;
    if (t < 131072) { wprep_one(F2, Bf2, 512, 512, 256, t); return; }
}

__global__ void k_split(const float* __restrict__ in, half_t* __restrict__ out, int K) {
    int t = blockIdx.x * 256 + threadIdx.x;
    int row = t / K, k = t % K;
    float v = in[t];
    half_t h = (half_t)v;
    half_t l = (half_t)(v - (float)h);
    half_t* o = out + (size_t)row * 2 * K;
    o[k] = h;
    o[K + k] = l;
}

// ---------------- MFMA GEMM, BN=128 (L1 + head) ----------------

template <bool RELU>
__global__ __launch_bounds__(256, 2)
void k_mgemm(const half_t* __restrict__ Ap, const half_t* __restrict__ Bt,
             const float* __restrict__ bias, float* __restrict__ C,
             int M, int Kpad, int Nc) {
    __shared__ half_t As[128 * 64];
    __shared__ half_t Bs[128 * 64];
    const int tid = threadIdx.x;
    const int wave = tid >> 6, lane = tid & 63;
    const int wm = wave >> 1, wn = wave & 1;
    const int bm = blockIdx.x * 128, bn = blockIdx.y * 128;
    const int KA = 2 * Kpad, KB = 3 * Kpad;
    const int nkt = KB >> 6;
    const int aTiles = KA >> 6;

    f32x4 acc[4][4] = {};

    const int srow = tid >> 3;
    const int ch = tid & 7;

    for (int kt = 0; kt < nkt; ++kt) {
        int ka0 = ((kt < aTiles) ? kt : (kt - aTiles)) << 6;
        int kb0 = kt << 6;
        __syncthreads();
#pragma unroll
        for (int i = 0; i < 4; ++i) {
            int rl = i * 32 + srow;
            int sch = ch ^ (rl & 7);
            int gr = bm + rl; if (gr >= M) gr = M - 1;
            const half_t* ga = Ap + (size_t)gr * KA + ka0 + sch * 8;
            GLOAD_LDS(ga, (char*)As + i * 4096 + wave * 1024);
        }
#pragma unroll
        for (int i = 0; i < 4; ++i) {
            int rl = i * 32 + srow;
            int sch = ch ^ (rl & 7);
            const half_t* gb = Bt + (size_t)(bn + rl) * KB + kb0 + sch * 8;
            GLOAD_LDS(gb, (char*)Bs + i * 4096 + wave * 1024);
        }
        __syncthreads();
#pragma unroll
        for (int s = 0; s < 2; ++s) {
            f16x8 af[4], bf[4];
#pragma unroll
            for (int i = 0; i < 4; ++i) {
                int row = wm * 64 + i * 16 + (lane & 15);
                int c = s * 4 + (lane >> 4);
                af[i] = *(const f16x8*)&As[row * 64 + ((c ^ (row & 7)) << 3)];
            }
#pragma unroll
            for (int j = 0; j < 4; ++j) {
                int row = wn * 64 + j * 16 + (lane & 15);
                int c = s * 4 + (lane >> 4);
                bf[j] = *(const f16x8*)&Bs[row * 64 + ((c ^ (row & 7)) << 3)];
            }
#pragma unroll
            for (int i = 0; i < 4; ++i)
#pragma unroll
                for (int j = 0; j < 4; ++j)
                    acc[i][j] = __builtin_amdgcn_mfma_f32_16x16x32_f16(af[i], bf[j], acc[i][j], 0, 0, 0);
        }
    }

#pragma unroll
    for (int i = 0; i < 4; ++i) {
#pragma unroll
        for (int j = 0; j < 4; ++j) {
            int cc = bn + wn * 64 + j * 16 + (lane & 15);
            float bv = bias[cc];
            int r0 = bm + wm * 64 + i * 16 + (lane >> 4) * 4;
#pragma unroll
            for (int q = 0; q < 4; ++q) {
                int gr = r0 + q;
                if (gr < M) {
                    float v = acc[i][j][q] + bv;
                    if (RELU) v = fmaxf(v, 0.f);
                    C[(size_t)gr * Nc + cc] = v;
                }
            }
        }
    }
}

// ---------------- MFMA GEMM, BN=256 (node layers L2-L4, Nc==256) ----------------
// One block covers all 256 output cols for its 128-row panel -> A read once per sweep.

template <bool RELU>
__global__ __launch_bounds__(256, 2)
void k_mgemm256(const half_t* __restrict__ Ap, const half_t* __restrict__ Bt,
                const float* __restrict__ bias, float* __restrict__ C,
                int M, int Kpad) {
    __shared__ half_t As[128 * 64];
    __shared__ half_t Bs[256 * 64];
    const int tid = threadIdx.x;
    const int wave = tid >> 6, lane = tid & 63;
    const int wm = wave >> 1, wn = wave & 1;   // rows: wm*64; cols: wn*128
    const int bm = blockIdx.x * 128;
    const int KA = 2 * Kpad, KB = 3 * Kpad;
    const int nkt = KB >> 6;
    const int aTiles = KA >> 6;

    f32x4 acc[4][8] = {};

    const int srow = tid >> 3;
    const int ch = tid & 7;

    for (int kt = 0; kt < nkt; ++kt) {
        int ka0 = ((kt < aTiles) ? kt : (kt - aTiles)) << 6;
        int kb0 = kt << 6;
        __syncthreads();
#pragma unroll
        for (int i = 0; i < 4; ++i) {
            int rl = i * 32 + srow;
            int sch = ch ^ (rl & 7);
            int gr = bm + rl; if (gr >= M) gr = M - 1;
            const half_t* ga = Ap + (size_t)gr * KA + ka0 + sch * 8;
            GLOAD_LDS(ga, (char*)As + i * 4096 + wave * 1024);
        }
#pragma unroll
        for (int i = 0; i < 8; ++i) {
            int rl = i * 32 + srow;                 // Bt row (output col) 0..255
            int sch = ch ^ (rl & 7);
            const half_t* gb = Bt + (size_t)rl * KB + kb0 + sch * 8;
            GLOAD_LDS(gb, (char*)Bs + i * 4096 + wave * 1024);
        }
        __syncthreads();
#pragma unroll
        for (int s = 0; s < 2; ++s) {
            f16x8 af[4], bf[8];
#pragma unroll
            for (int i = 0; i < 4; ++i) {
                int row = wm * 64 + i * 16 + (lane & 15);
                int c = s * 4 + (lane >> 4);
                af[i] = *(const f16x8*)&As[row * 64 + ((c ^ (row & 7)) << 3)];
            }
#pragma unroll
            for (int j = 0; j < 8; ++j) {
                int row = wn * 128 + j * 16 + (lane & 15);
                int c = s * 4 + (lane >> 4);
                bf[j] = *(const f16x8*)&Bs[row * 64 + ((c ^ (row & 7)) << 3)];
            }
#pragma unroll
            for (int i = 0; i < 4; ++i)
#pragma unroll
                for (int j = 0; j < 8; ++j)
                    acc[i][j] = __builtin_amdgcn_mfma_f32_16x16x32_f16(af[i], bf[j], acc[i][j], 0, 0, 0);
        }
    }

#pragma unroll
    for (int i = 0; i < 4; ++i) {
#pragma unroll
        for (int j = 0; j < 8; ++j) {
            int cc = wn * 128 + j * 16 + (lane & 15);
            float bv = bias[cc];
            int r0 = bm + wm * 64 + i * 16 + (lane >> 4) * 4;
#pragma unroll
            for (int q = 0; q < 4; ++q) {
                int gr = r0 + q;
                if (gr < M) {
                    float v = acc[i][j][q] + bv;
                    if (RELU) v = fmaxf(v, 0.f);
                    C[(size_t)gr * 256 + cc] = v;
                }
            }
        }
    }
}

// ---------------- pooling ----------------

__global__ void k_pool(const float* __restrict__ act, const int* __restrict__ gstart,
                       float* __restrict__ h) {
    int g = blockIdx.x;
    int f = threadIdx.x;
    int s = gstart[g], e = gstart[g + 1];
    float mx = 0.f, sm = 0.f;
    for (int i = s; i < e; ++i) {
        float v = act[(size_t)i * 256 + f];
        mx = fmaxf(mx, v);
        sm += v;
    }
    float cnt = (float)(e - s);
    h[(size_t)g * 512 + f] = mx;
    h[(size_t)g * 512 + 256 + f] = (cnt > 0.f) ? sm / cnt : 0.f;
}

// ---------------- head ----------------

__global__ void k_headin_split(const float* __restrict__ h, half_t* __restrict__ xh) {
    int t = blockIdx.x * blockDim.x + threadIdx.x;
    if (t >= GG * 1024) return;
    int g = t >> 10, j = t & 1023;
    const float* h1 = h + (size_t)g * 512;
    const float* h2 = h + (size_t)(GG + g) * 512;
    float v = (j < 512) ? (h1[j] - h2[j]) : (h2[j - 512] - h1[j - 512]);
    half_t hi = (half_t)v;
    half_t lo = (half_t)(v - (float)hi);
    half_t* o = xh + (size_t)g * 2048;
    o[j] = hi;
    o[1024 + j] = lo;
}

__global__ void k_fc3(const float* __restrict__ A, const float* __restrict__ W,
                      const float* __restrict__ b, float* __restrict__ out) {
    int g = blockIdx.x * 4 + (threadIdx.x >> 6);
    int lane = threadIdx.x & 63;
    const float* a = A + (size_t)g * 256;
    float p = a[lane] * W[lane] + a[lane + 64] * W[lane + 64]
            + a[lane + 128] * W[lane + 128] + a[lane + 192] * W[lane + 192];
    for (int off = 32; off > 0; off >>= 1) p += __shfl_down(p, off);
    if (lane == 0) out[g] = tanhf(p + b[0]);
}

// ---------------- launch ----------------

extern "C" void kernel_launch(void* const* d_in, const int* in_sizes, int n_in,
                              void* d_out, int out_size, void* d_ws, size_t ws_size,
                              hipStream_t stream) {
    const float* x1  = (const float*)d_in[0];
    const int*   ei1 = (const int*)d_in[1];
    const int*   ba1 = (const int*)d_in[2];
    const float* x2  = (const float*)d_in[3];
    const int*   ei2 = (const int*)d_in[4];
    const int*   ba2 = (const int*)d_in[5];
    const float* W1 = (const float*)d_in[6];
    const float* b1 = (const float*)d_in[7];
    const float* W2 = (const float*)d_in[8];
    const float* b2 = (const float*)d_in[9];
    const float* W3 = (const float*)d_in[10];
    const float* b3 = (const float*)d_in[11];
    const float* W4 = (const float*)d_in[12];
    const float* b4 = (const float*)d_in[13];
    const float* fc1W = (const float*)d_in[14];
    const float* fc1b = (const float*)d_in[15];
    const float* fc2W = (const float*)d_in[16];
    const float* fc2b = (const float*)d_in[17];
    const float* fc3W = (const float*)d_in[18];
    const float* fc3b = (const float*)d_in[19];
    float* out = (float*)d_out;

    char* ws = (char*)d_ws;
    size_t off = 0;
    auto alloc = [&](size_t bytes) -> void* {
        void* p = (void*)(ws + off);
        off += (bytes + 255) & ~(size_t)255;
        return p;
    };
    int*    dc     = (int*)alloc((size_t)4 * NN * sizeof(int));   // deg[2N] | cnt[2N]
    int*    rowptr = (int*)alloc((size_t)(2 * NN + 1) * sizeof(int));
    int*    colv   = (int*)alloc((size_t)2 * EE * sizeof(int));
    int*    bsum   = (int*)alloc(256 * sizeof(int));
    int*    boff   = (int*)alloc(256 * sizeof(int));
    int*    gstart = (int*)alloc((size_t)2 * (GG + 1) * sizeof(int));
    float*  dinv   = (float*)alloc((size_t)2 * NN * sizeof(float));
    half_t* Ap     = (half_t*)alloc((size_t)NN * 512 * sizeof(half_t));
    float*  act    = (float*)alloc((size_t)NN * 256 * sizeof(float));
    half_t* Bt1    = (half_t*)alloc((size_t)128 * 384 * sizeof(half_t));
    half_t* Bt2    = (half_t*)alloc((size_t)256 * 384 * sizeof(half_t));
    half_t* Bt3    = (half_t*)alloc((size_t)256 * 768 * sizeof(half_t));
    half_t* Bt4    = (half_t*)alloc((size_t)256 * 768 * sizeof(half_t));
    half_t* Btf1   = (half_t*)alloc((size_t)512 * 3072 * sizeof(half_t));
    half_t* Btf2   = (half_t*)alloc((size_t)256 * 1536 * sizeof(half_t));
    float*  hpool  = (float*)alloc((size_t)2 * GG * 512 * sizeof(float));
    half_t* xhs    = (half_t*)alloc((size_t)GG * 2048 * sizeof(half_t));
    float*  t1     = (float*)alloc((size_t)GG * 512 * sizeof(float));
    half_t* t1s    = (half_t*)alloc((size_t)GG * 1024 * sizeof(half_t));
    float*  t2     = (float*)alloc((size_t)GG * 256 * sizeof(float));

    int* deg = dc;
    int* cnt = dc + 2 * NN;

    int nsb2 = (2 * NN + 1023) / 1024;   // 196
    int mt = (NN + 127) / 128;           // 782

    // fused weight prep (one dispatch for all six matrices)
    k_wprep_all<<<(835584 + 255) / 256, 256, 0, stream>>>(W1, W2, W3, W4, fc1W, fc2W,
                                                          Bt1, Bt2, Bt3, Bt4, Btf1, Btf2);

    // merged CSR build (once for both encoders)
    hipMemsetAsync(dc, 0, (size_t)4 * NN * sizeof(int), stream);
    k_count2<<<(2 * EE + 255) / 256, 256, 0, stream>>>(ei1, ei2, deg);
    k_scan_bsum<<<nsb2, 256, 0, stream>>>(deg, bsum, 2 * NN);
    k_scan_off<<<1, 256, 0, stream>>>(bsum, boff, nsb2);
    k_scan_write<<<nsb2, 256, 0, stream>>>(deg, boff, rowptr, dinv, 2 * NN, 2 * EE);
    k_fill2<<<(2 * EE + 255) / 256, 256, 0, stream>>>(ei1, ei2, rowptr, cnt, colv);
    k_starts2<<<(2 * NN + 255) / 256, 256, 0, stream>>>(ba1, ba2, gstart);

    for (int p = 0; p < 2; ++p) {
        const float* x  = p ? x2 : x1;
        const int*   rp = rowptr + p * NN;
        const float* dv = dinv + p * NN;
        const int*   gs = gstart + p * (GG + 1);

        // L1: agg90 -> Ap[N][256]h; BN=128 gemm -> act[N,128]
        k_agg90<<<(NN + 3) / 4, 256, 0, stream>>>(x, dv, rp, colv, Ap);
        k_mgemm<true><<<dim3(mt, 1), 256, 0, stream>>>(Ap, Bt1, b1, act, NN, 128, 128);
        // L2: F=128 gather -> Ap[N][256]h; BN=256 gemm -> act[N,256]
        k_agg_splitv<2><<<(NN + 3) / 4, 256, 0, stream>>>(act, dv, rp, colv, Ap);
        k_mgemm256<true><<<mt, 256, 0, stream>>>(Ap, Bt2, b2, act, NN, 128);
        // L3: F=256 gather -> Ap[N][512]h; BN=256 gemm
        k_agg_splitv<4><<<(NN + 3) / 4, 256, 0, stream>>>(act, dv, rp, colv, Ap);
        k_mgemm256<true><<<mt, 256, 0, stream>>>(Ap, Bt3, b3, act, NN, 256);
        // L4
        k_agg_splitv<4><<<(NN + 3) / 4, 256, 0, stream>>>(act, dv, rp, colv, Ap);
        k_mgemm256<true><<<mt, 256, 0, stream>>>(Ap, Bt4, b4, act, NN, 256);

        k_pool<<<GG, 256, 0, stream>>>(act, gs, hpool + (size_t)p * GG * 512);
    }

    // head: split-precision MFMA for fc1/fc2, wave-reduce for fc3
    k_headin_split<<<(GG * 1024 + 255) / 256, 256, 0, stream>>>(hpool, xhs);
    k_mgemm<true><<<dim3(GG / 128, 4), 256, 0, stream>>>(xhs, Btf1, fc1b, t1, GG, 1024, 512);
    k_split<<<(GG * 512 + 255) / 256, 256, 0, stream>>>(t1, t1s, 512);
    k_mgemm<true><<<dim3(GG / 128, 2), 256, 0, stream>>>(t1s, Btf2, fc2b, t2, GG, 512, 256);
    k_fc3<<<GG / 4, 256, 0, stream>>>(t2, fc3W, fc3b, out);
}